// Round 3
// baseline (794.752 us; speedup 1.0000x reference)
//
#include <hip/hip_runtime.h>
#include <stdint.h>
#include <stddef.h>

#define BATCH 65536
#define DIN   256
#define HDIM  512
#define KDIM  768           // Din + H
#define NDIM  2048          // 4*H, gate-interleaved packing
#define HN_ELEMS (BATCH * HDIM)

using f32x4 = __attribute__((ext_vector_type(4))) float;
using s16x8 = __attribute__((ext_vector_type(8))) short;
using u16x8 = __attribute__((ext_vector_type(8))) unsigned short;
using u32x4 = __attribute__((ext_vector_type(4))) unsigned int;

__device__ __forceinline__ unsigned short f2bf(float f) {
    union { float f; unsigned u; } v; v.f = f;
    unsigned r = v.u + 0x7fffu + ((v.u >> 16) & 1u);   // RNE
    return (unsigned short)(r >> 16);
}

// packed f32x2 -> bf16x2 (lo = src0, hi = src1), RNE. No builtin on gfx950 (m240).
__device__ __forceinline__ unsigned pk2(float lo, float hi) {
    unsigned r;
    asm("v_cvt_pk_bf16_f32 %0, %1, %2" : "=v"(r) : "v"(lo), "v"(hi));
    return r;
}

#define GLDS(gptr, lptr) __builtin_amdgcn_global_load_lds( \
    (const __attribute__((address_space(1))) void*)(gptr), \
    (__attribute__((address_space(3))) void*)(lptr), 16, 0, 0)

// ---------------------------------------------------------------------------
// Pack weights bf16 B^T via LDS transpose (old version read one COLUMN per
// wave at stride 2KB: 16x overfetch, ~300us). Block = 64k x 64h tile of one
// gate: coalesced f32x4 loads, LDS transpose, coalesced 16B wPack stores.
// n = (h>>4)*64 + g*16 + (h&15).
// ---------------------------------------------------------------------------
__global__ __launch_bounds__(256) void pack_w_kernel(
    const float* __restrict__ U, const float* __restrict__ W,
    unsigned short* __restrict__ wPack)
{
    __shared__ __align__(16) unsigned short lt[64 * 72];   // [h][k+pad]
    const int t  = threadIdx.x;
    const int b  = blockIdx.x;          // 384 blocks
    const int g  = b & 3;
    const int ht = (b >> 2) & 7;
    const int kt = b >> 5;              // 0..11
    const int k0 = kt * 64;
    const int h0 = ht * 64;
    const int c0 = (t & 15) * 4;        // h col within tile
    const int r0 = t >> 4;              // k row within tile (0..15)

    const float* src = (k0 < DIN)
        ? (U + (size_t)(g * DIN + k0 + r0) * HDIM + h0 + c0)
        : (W + (size_t)(g * HDIM + (k0 - DIN) + r0) * HDIM + h0 + c0);
#pragma unroll
    for (int rr = 0; rr < 4; ++rr) {
        f32x4 v = *(const f32x4*)(src + (size_t)rr * 16 * HDIM);
        const int r = r0 + rr * 16;
#pragma unroll
        for (int j = 0; j < 4; ++j)
            lt[(c0 + j) * 72 + r] = f2bf(v[j]);
    }
    __syncthreads();
#pragma unroll
    for (int it = 0; it < 2; ++it) {
        const int hl = (t >> 3) + it * 32;
        const int ks = t & 7;
        const int n  = (ht * 4 + (hl >> 4)) * 64 + g * 16 + (hl & 15);
        *(u16x8*)(wPack + (size_t)n * KDIM + k0 + ks * 8) =
            *(const u16x8*)&lt[hl * 72 + ks * 8];
    }
}

__global__ __launch_bounds__(256) void pack_bias_kernel(
    const float* __restrict__ bU, const float* __restrict__ bW,
    float* __restrict__ bias)
{
    int n = blockIdx.x * 256 + threadIdx.x;   // 2048 total
    int g = (n >> 4) & 3;
    int h = ((n >> 6) << 4) | (n & 15);
    bias[n] = bU[g * HDIM + h] + bW[g * HDIM + h];
}

// ---------------------------------------------------------------------------
// Fused pack(A f32->bf16) + GEMM + LSTM epilogue.
// 128x128 tile, BK=32, 4 waves (2x2), wave tile 64x64.
// Pipeline: B triple-buffered via global_load_lds (prefetch distance 2),
// A double-buffered via reg-load + cvt_pk + ds_write (distance 1).
// Raw s_barrier with COUNTED s_waitcnt vmcnt(2): next-next B tile's loads
// stay in flight across the barrier (T4). A reg-loads are issued BEFORE the
// gl_lds pair so the pk2 consumption waits to vmcnt(2), never 0.
// LDS: A[2][128][32] | B[3][128][32] bf16 = 40 KB -> 4 blocks/CU at 128 regs.
// Swizzle (unchanged): 16B slot p of row r holds global chunk p ^ ((r>>2)&3).
// ---------------------------------------------------------------------------
__global__ __launch_bounds__(256, 3) void lstm_fused_kernel(
    const float* __restrict__ x,
    const float* __restrict__ hOld,
    const unsigned short* __restrict__ wPack,
    const float* __restrict__ bias,
    const float* __restrict__ cOld,
    float* __restrict__ out)
{
    __shared__ __align__(16) unsigned short smem[20480];   // 40 KB

    const int tid = threadIdx.x;
    const int w  = tid >> 6;          // wave 0..3
    const int l  = tid & 63;
    const int wm = w >> 1;
    const int wn = w & 1;
    const int lq = l >> 4;            // quad 0..3
    const int lc = l & 15;

    // bijective XCD chunking: 8192 wgs, 8 XCDs, 1024/XCD; N fastest within.
    const int bid = blockIdx.x;
    const int wg  = (bid & 7) * 1024 + (bid >> 3);
    const int nt  = wg & 15;          // 0..15
    const int mt  = wg >> 4;          // 0..511
    const int m0  = mt * 128;
    const int n0  = nt * 128;

    // ---- A staging: thread -> (row ar, k-half ah*16). 16 f32 -> 2 chunks ----
    const int ar = tid >> 1;          // 0..127
    const int ah = tid & 1;
    const float* xrow = x    + (size_t)(m0 + ar) * DIN  + ah * 16;
    const float* hrow = hOld + (size_t)(m0 + ar) * HDIM + ah * 16;
    const int akey = (ar >> 2) & 3;
    const int as0 = ((ah * 2)     ^ akey) * 8;   // short offsets within row
    const int as1 = ((ah * 2 + 1) ^ akey) * 8;

    // ---- B staging: 2 gl_lds per thread; pre-swizzled global chunk ----
    const int brow_l = l >> 2;                       // 0..15
    const int bchunk = (l & 3) ^ ((l >> 4) & 3);
    const unsigned short* gb0 = wPack + (size_t)(n0 + w * 16 + brow_l) * KDIM + bchunk * 8;
    const unsigned short* gb1 = gb0 + (size_t)64 * KDIM;

    const int swz = (lc >> 2) & 3;    // fragment read-side swizzle

    f32x4 acc[4][4];
#pragma unroll
    for (int i = 0; i < 4; ++i)
#pragma unroll
        for (int j = 0; j < 4; ++j)
            acc[i][j] = (f32x4){0.f, 0.f, 0.f, 0.f};

    // ---- prologue: A tile0 -> Abuf0; B tile0 -> Bbuf0, tile1 -> Bbuf1 ----
    {
        f32x4 av0 = ((const f32x4*)xrow)[0];
        f32x4 av1 = ((const f32x4*)xrow)[1];
        f32x4 av2 = ((const f32x4*)xrow)[2];
        f32x4 av3 = ((const f32x4*)xrow)[3];
        GLDS(gb0,      &smem[8192 + w * 512]);
        GLDS(gb1,      &smem[8192 + 2048 + w * 512]);
        GLDS(gb0 + 32, &smem[8192 + 4096 + w * 512]);
        GLDS(gb1 + 32, &smem[8192 + 4096 + 2048 + w * 512]);
        u32x4 o0, o1;
        o0[0] = pk2(av0[0], av0[1]); o0[1] = pk2(av0[2], av0[3]);
        o0[2] = pk2(av1[0], av1[1]); o0[3] = pk2(av1[2], av1[3]);
        o1[0] = pk2(av2[0], av2[1]); o1[1] = pk2(av2[2], av2[3]);
        o1[2] = pk2(av3[0], av3[1]); o1[3] = pk2(av3[2], av3[3]);
        *(u32x4*)&smem[ar * 32 + as0] = o0;
        *(u32x4*)&smem[ar * 32 + as1] = o1;
        asm volatile("s_waitcnt vmcnt(2) lgkmcnt(0)" ::: "memory");
        __builtin_amdgcn_s_barrier();
        __builtin_amdgcn_sched_barrier(0);
    }

    // step: compute on (ab, bb); prefetch A tile kt+1 (regs->cvt->Abuf ab^1),
    // B tile kt+2 (gl_lds -> Bbuf nb). wmode: 0 = vmcnt(2) raw barrier,
    // 1 = vmcnt(0) raw barrier, 2 = __syncthreads.
    auto step = [&](int kt, bool pfa, bool pfb, int ab, int bb, int nb, int wmode) {
        f32x4 av0, av1, av2, av3;
        if (pfa) {
            const int k2 = kt + 1;
            const float* s = (k2 < 8) ? (xrow + k2 * 32) : (hrow + (k2 - 8) * 32);
            av0 = ((const f32x4*)s)[0];
            av1 = ((const f32x4*)s)[1];
            av2 = ((const f32x4*)s)[2];
            av3 = ((const f32x4*)s)[3];
        }
        if (pfb) {
            const int k3 = (kt + 2) * 32;
            unsigned short* lb = &smem[8192 + nb * 4096];
            GLDS(gb0 + k3, lb + w * 512);
            GLDS(gb1 + k3, lb + 2048 + w * 512);
        }
        // compute on (ab, bb)
        {
            const int abase = ab * 4096;
            const int bbase = 8192 + bb * 4096;
            s16x8 af[4], bf4[4];
#pragma unroll
            for (int i = 0; i < 4; ++i)
                af[i] = *(const s16x8*)&smem[abase + (wm * 64 + i * 16 + lc) * 32 + (lq ^ swz) * 8];
#pragma unroll
            for (int j = 0; j < 4; ++j)
                bf4[j] = *(const s16x8*)&smem[bbase + (wn * 64 + j * 16 + lc) * 32 + (lq ^ swz) * 8];
            __builtin_amdgcn_s_setprio(1);
#pragma unroll
            for (int i = 0; i < 4; ++i)
#pragma unroll
                for (int j = 0; j < 4; ++j)
                    acc[i][j] = __builtin_amdgcn_mfma_f32_16x16x32_bf16(
                        af[i], bf4[j], acc[i][j], 0, 0, 0);
            __builtin_amdgcn_s_setprio(0);
        }
        if (pfa) {
            u32x4 o0, o1;
            o0[0] = pk2(av0[0], av0[1]); o0[1] = pk2(av0[2], av0[3]);
            o0[2] = pk2(av1[0], av1[1]); o0[3] = pk2(av1[2], av1[3]);
            o1[0] = pk2(av2[0], av2[1]); o1[1] = pk2(av2[2], av2[3]);
            o1[2] = pk2(av3[0], av3[1]); o1[3] = pk2(av3[2], av3[3]);
            const int abn = (ab ^ 1) * 4096;
            *(u32x4*)&smem[abn + ar * 32 + as0] = o0;
            *(u32x4*)&smem[abn + ar * 32 + as1] = o1;
        }
        if (wmode == 0) {
            asm volatile("s_waitcnt vmcnt(2) lgkmcnt(0)" ::: "memory");
            __builtin_amdgcn_s_barrier();
            __builtin_amdgcn_sched_barrier(0);
        } else if (wmode == 1) {
            asm volatile("s_waitcnt vmcnt(0) lgkmcnt(0)" ::: "memory");
            __builtin_amdgcn_s_barrier();
            __builtin_amdgcn_sched_barrier(0);
        } else {
            __syncthreads();
        }
    };

    // main: 18 steps (buffer rotation period 6), all prefetches active
#pragma unroll 1
    for (int kb = 0; kb < 18; kb += 6) {
        step(kb + 0, true, true, 0, 0, 2, 0);
        step(kb + 1, true, true, 1, 1, 0, 0);
        step(kb + 2, true, true, 0, 2, 1, 0);
        step(kb + 3, true, true, 1, 0, 2, 0);
        step(kb + 4, true, true, 0, 1, 0, 0);
        step(kb + 5, true, true, 1, 2, 1, 0);
    }
    // tail: steps 18..23 with static prefetch predicates
    step(18, true,  true,  0, 0, 2, 0);
    step(19, true,  true,  1, 1, 0, 0);
    step(20, true,  true,  0, 2, 1, 0);
    step(21, true,  true,  1, 0, 2, 0);
    step(22, true,  false, 0, 1, 0, 1);   // drain: tile-23 B must land
    step(23, false, false, 1, 2, 0, 2);

    // ---- epilogue: j = gate (i,f,o,c); LDS-transposed full-line stores ----
    const int nbase = n0 + wn * 64;
    const float b0 = bias[nbase +  0 + lc];
    const float b1 = bias[nbase + 16 + lc];
    const float b2 = bias[nbase + 32 + lc];
    const float b3 = bias[nbase + 48 + lc];
    const int hcol = (n0 >> 2) + wn * 16 + lc;

    float co[4][4];
#pragma unroll
    for (int i = 0; i < 4; ++i)
#pragma unroll
        for (int r = 0; r < 4; ++r)
            co[i][r] = cOld[(size_t)(m0 + wm * 64 + i * 16 + lq * 4 + r) * HDIM + hcol];

    float* fsm  = (float*)smem;
    float* hn_t = fsm;            // 32 cols x stride 36 = 1152 floats
    float* cn_t = fsm + 1152;     // total 9216 B < 40 KB

#pragma unroll
    for (int i = 0; i < 4; ++i) {
        f32x4 hnv, cnv;
#pragma unroll
        for (int r = 0; r < 4; ++r) {
            const float gi = acc[i][0][r] + b0;
            const float gf = acc[i][1][r] + b1;
            const float go = acc[i][2][r] + b2;
            const float gc = acc[i][3][r] + b3;
            const float it = 1.f / (1.f + __expf(-gi));
            const float ft = 1.f / (1.f + __expf(-gf));
            const float ot = 1.f / (1.f + __expf(-go));
            const float ct = 2.f / (1.f + __expf(-2.f * gc)) - 1.f;
            const float cn = it * ct + ft * co[i][r];
            const float tc = 2.f / (1.f + __expf(-2.f * cn)) - 1.f;
            cnv[r] = cn;
            hnv[r] = ot * tc;
        }
        __syncthreads();   // previous chunk's phase-B reads done
        {
            const int addr = (wn * 16 + lc) * 36 + wm * 16 + lq * 4;
            *(f32x4*)&hn_t[addr] = hnv;
            *(f32x4*)&cn_t[addr] = cnv;
        }
        __syncthreads();
        // phase B: full-line coalesced stores. 8 threads/row x 32 rows.
        {
            const int rloc = tid >> 3;          // 0..31
            const int cg   = tid & 7;           // 0..7 -> 4 cols each
            const int grow = m0 + (rloc >> 4) * 64 + i * 16 + (rloc & 15);
            f32x4 hv, cv;
#pragma unroll
            for (int c = 0; c < 4; ++c) {
                hv[c] = hn_t[(cg * 4 + c) * 36 + rloc];
                cv[c] = cn_t[(cg * 4 + c) * 36 + rloc];
            }
            const size_t ob = (size_t)grow * HDIM + (n0 >> 2) + cg * 4;
            *(f32x4*)&out[ob] = hv;
            *(f32x4*)&out[(size_t)HN_ELEMS + ob] = cv;
        }
    }
}

extern "C" void kernel_launch(void* const* d_in, const int* in_sizes, int n_in,
                              void* d_out, int out_size, void* d_ws, size_t ws_size,
                              hipStream_t stream)
{
    const float* x     = (const float*)d_in[0];
    const float* h_old = (const float*)d_in[1];
    const float* c_old = (const float*)d_in[2];
    const float* U     = (const float*)d_in[3];
    const float* bU    = (const float*)d_in[4];
    const float* W     = (const float*)d_in[5];
    const float* bW    = (const float*)d_in[6];
    float* out = (float*)d_out;

    unsigned short* wPack = (unsigned short*)d_ws;                                 // 3 MB
    float* bias = (float*)((char*)d_ws + (size_t)NDIM * KDIM * 2);                 // 8 KB

    pack_w_kernel<<<dim3(384), dim3(256), 0, stream>>>(U, W, wPack);
    pack_bias_kernel<<<dim3(8), dim3(256), 0, stream>>>(bU, bW, bias);
    lstm_fused_kernel<<<dim3(8192), dim3(256), 0, stream>>>(x, h_old, wPack, bias, c_old, out);
}